// Round 1
// baseline (385.060 us; speedup 1.0000x reference)
//
#include <hip/hip_runtime.h>

typedef float f32x4 __attribute__((ext_vector_type(4)));
typedef short bf16x8 __attribute__((ext_vector_type(8)));

// ---------- helpers ----------
__device__ __forceinline__ unsigned int pk2(float a, float b) {
    // pack: low16 = bf16_rne(a), high16 = bf16_rne(b)
    unsigned int ua = __float_as_uint(a); ua += 0x7FFFu + ((ua >> 16) & 1u);
    unsigned int ub = __float_as_uint(b); ub += 0x7FFFu + ((ub >> 16) & 1u);
    return __builtin_amdgcn_perm(ub, ua, 0x07060302u);
}
__device__ __forceinline__ unsigned short bf16_rne(float a) {
    unsigned int ua = __float_as_uint(a);
    ua += 0x7FFFu + ((ua >> 16) & 1u);
    return (unsigned short)(ua >> 16);
}
__device__ __forceinline__ float tanh_fast(float x) {
    float e = __expf(x + x);
    return 1.f - 2.f / (e + 1.f);
}
__device__ __forceinline__ f32x4 mfma16(bf16x8 a, bf16x8 b, f32x4 c) {
    return __builtin_amdgcn_mfma_f32_16x16x32_bf16(a, b, c, 0, 0, 0);
}

// ---------- 1. bulk fp32 -> bf16 conversion / assembly ----------
// segments (in float4 "quads"):
#define Q_WIH   786432
#define Q_WHH   1572864
#define Q_QW    1703936
#define Q_X2    1720320
#define Q_X1    1736704
#define Q_BAW   1802240
#define Q_BLW   1806336
#define Q_EB    1806464

__global__ __launch_bounds__(256) void k_convert(
    const float* __restrict__ Wih, const float* __restrict__ Whh,
    const float* __restrict__ qw, const float* __restrict__ rnn_state,
    const float* __restrict__ memory, const float* __restrict__ context,
    const float* __restrict__ aw, const float* __restrict__ lw,
    const float* __restrict__ ab, const float* __restrict__ lb,
    unsigned short* __restrict__ Wihb, unsigned short* __restrict__ Whhb,
    unsigned short* __restrict__ qwb, unsigned short* __restrict__ X2b,
    unsigned short* __restrict__ X1b, unsigned short* __restrict__ Bbig,
    float* __restrict__ ebias)
{
    int q = blockIdx.x * 256 + threadIdx.x;
    if (q >= Q_EB) return;
    if (q < Q_WIH) {
        int i = q * 4;
        float4 v = *(const float4*)(Wih + i);
        uint2 u; u.x = pk2(v.x, v.y); u.y = pk2(v.z, v.w);
        *(uint2*)(Wihb + i) = u;
    } else if (q < Q_WHH) {
        int i = (q - Q_WIH) * 4;
        float4 v = *(const float4*)(Whh + i);
        uint2 u; u.x = pk2(v.x, v.y); u.y = pk2(v.z, v.w);
        *(uint2*)(Whhb + i) = u;
    } else if (q < Q_QW) {
        int i = (q - Q_WHH) * 4;
        float4 v = *(const float4*)(qw + i);
        uint2 u; u.x = pk2(v.x, v.y); u.y = pk2(v.z, v.w);
        *(uint2*)(qwb + i) = u;
    } else if (q < Q_X2) {
        int i = (q - Q_QW) * 4;
        float4 v = *(const float4*)(rnn_state + i);
        uint2 u; u.x = pk2(v.x, v.y); u.y = pk2(v.z, v.w);
        *(uint2*)(X2b + i) = u;
    } else if (q < Q_X1) {
        int i = (q - Q_X2) * 4;
        int b = i >> 10, c = i & 1023;
        const float* s = (c < 512) ? (memory + b * 512 + c) : (context + b * 512 + (c - 512));
        float4 v = *(const float4*)s;
        uint2 u; u.x = pk2(v.x, v.y); u.y = pk2(v.z, v.w);
        *(uint2*)(X1b + i) = u;
    } else if (q < Q_BAW) {
        int i = (q - Q_X1) * 4;
        int a = i >> 9, c = i & 511;
        float4 v = *(const float4*)(aw + a * 512 + c);
        uint2 u; u.x = pk2(v.x, v.y); u.y = pk2(v.z, v.w);
        *(uint2*)(Bbig + a * 544 + c) = u;
    } else if (q < Q_BLW) {
        int i = (q - Q_BAW) * 4;
        int a = i >> 5, c = i & 31;
        float4 v = *(const float4*)(lw + a * 32 + c);
        uint2 u; u.x = pk2(v.x, v.y); u.y = pk2(v.z, v.w);
        *(uint2*)(Bbig + a * 544 + 512 + c) = u;
    } else {
        int i = (q - Q_BLW) * 4;
        float4 va = *(const float4*)(ab + i);
        float4 vb = *(const float4*)(lb + i);
        float4 r; r.x = va.x + vb.x; r.y = va.y + vb.y; r.z = va.z + vb.z; r.w = va.w + vb.w;
        *(float4*)(ebias + i) = r;
    }
}

// ---------- 2. location conv: atten [64,2,1024] -> Lconv bf16 [bt][32] ----------
__global__ __launch_bounds__(256) void k_conv(
    const float* __restrict__ atten, const float* __restrict__ convw,
    unsigned short* __restrict__ Lconv)
{
    __shared__ float att_s[2 * 160];
    __shared__ float cw_s[1984];
    const int b = blockIdx.x >> 3;
    const int tbase = (blockIdx.x & 7) * 128;
    const int tid = threadIdx.x;
    for (int i = tid; i < 320; i += 256) {
        int c = i / 160, j = i % 160;
        float v = 0.f;
        int pos = tbase - 15 + j;
        if (j < 158 && pos >= 0 && pos < 1024) v = atten[b * 2048 + c * 1024 + pos];
        att_s[c * 160 + j] = v;
    }
    for (int i = tid; i < 1984; i += 256) cw_s[i] = convw[i];
    __syncthreads();
    const int f = tid & 31, tq = tid >> 5;
    float acc[16];
#pragma unroll
    for (int i = 0; i < 16; ++i) acc[i] = 0.f;
    for (int c = 0; c < 2; ++c) {
        for (int k = 0; k < 31; ++k) {
            float w = cw_s[f * 62 + c * 31 + k];
            int base = c * 160 + tq * 16 + k;
#pragma unroll
            for (int ti = 0; ti < 16; ++ti) acc[ti] += w * att_s[base + ti];
        }
    }
#pragma unroll
    for (int ti = 0; ti < 16; ++ti) {
        int t = tbase + tq * 16 + ti;
        Lconv[(b * 1024 + t) * 32 + f] = bf16_rne(acc[ti]);
    }
}

// ---------- 3. generic M=64 MFMA GEMM: C[64,N] = A @ B^T + bias ----------
// A1/B1 for cols < n_split, A2/B2 (row offset -n_split) otherwise. bf16 inputs.
__global__ __launch_bounds__(256, 2) void k_gemm128(
    const unsigned short* __restrict__ A1, const unsigned short* __restrict__ A2,
    const unsigned short* __restrict__ B1, const unsigned short* __restrict__ B2,
    const float* __restrict__ bias1, const float* __restrict__ bias2,
    float* __restrict__ C, int N, int n_split, int K)
{
    __shared__ __align__(16) unsigned short As[128 * 32];
    __shared__ __align__(16) unsigned short Bs[128 * 32];
    const int tid = threadIdx.x;
    const int nBase = blockIdx.x * 128;
    const bool use2 = nBase >= n_split;
    const unsigned short* A = use2 ? A2 : A1;
    const unsigned short* Bp = use2 ? B2 : B1;
    const float* bias = use2 ? bias2 : bias1;
    const int boff = use2 ? n_split : 0;

    const int lane = tid & 63, wave = tid >> 6;
    const int wrow = wave >> 1, wcol = wave & 1;
    const int c = lane & 15, qd = lane >> 4;
    const int sr = tid >> 2, sk = (tid & 3) * 8;

    { uint4 z = {0u, 0u, 0u, 0u}; *(uint4*)&As[(64 + sr) * 32 + sk] = z; }

    const f32x4 fz = {0.f, 0.f, 0.f, 0.f};
    f32x4 acc[4][4];
#pragma unroll
    for (int i = 0; i < 4; ++i)
#pragma unroll
        for (int j = 0; j < 4; ++j) acc[i][j] = fz;

    const int nk = K >> 5;
    for (int kc = 0; kc < nk; ++kc) {
        const int k0 = kc * 32;
        *(uint4*)&As[sr * 32 + sk] = *(const uint4*)&A[sr * K + k0 + sk];
        *(uint4*)&Bs[sr * 32 + sk] = *(const uint4*)&Bp[(nBase - boff + sr) * K + k0 + sk];
        *(uint4*)&Bs[(sr + 64) * 32 + sk] = *(const uint4*)&Bp[(nBase - boff + sr + 64) * K + k0 + sk];
        __syncthreads();
        bf16x8 af[4], bfr[4];
#pragma unroll
        for (int i = 0; i < 4; ++i) af[i] = *(const bf16x8*)&As[(wrow * 64 + i * 16 + c) * 32 + qd * 8];
#pragma unroll
        for (int j = 0; j < 4; ++j) bfr[j] = *(const bf16x8*)&Bs[(wcol * 64 + j * 16 + c) * 32 + qd * 8];
#pragma unroll
        for (int i = 0; i < 4; ++i)
#pragma unroll
            for (int j = 0; j < 4; ++j) acc[i][j] = mfma16(af[i], bfr[j], acc[i][j]);
        __syncthreads();
    }
#pragma unroll
    for (int i = 0; i < 4; ++i)
#pragma unroll
        for (int r = 0; r < 4; ++r) {
            int row = wrow * 64 + i * 16 + qd * 4 + r;
            if (row < 64) {
#pragma unroll
                for (int j = 0; j < 4; ++j) {
                    int col = nBase + wcol * 64 + j * 16 + c;
                    C[row * N + col] = acc[i][j][r] + bias[col - boff];
                }
            }
        }
}

// ---------- 4. GRU gates ----------
__global__ __launch_bounds__(256) void k_gates(
    const float* __restrict__ Cg, const float* __restrict__ h0,
    float* __restrict__ outv, unsigned short* __restrict__ X3b)
{
    int idx = blockIdx.x * 256 + threadIdx.x;
    int b = idx >> 10, h = idx & 1023;
    const float* g = Cg + b * 6144;
    float ir = g[h], iz = g[h + 1024], inn = g[h + 2048];
    float hr = g[h + 3072], hz = g[h + 4096], hn = g[h + 5120];
    float r = 1.f / (1.f + __expf(-(ir + hr)));
    float z = 1.f / (1.f + __expf(-(iz + hz)));
    float n = tanh_fast(inn + r * hn);
    float o = (1.f - z) * n + z * h0[idx];
    outv[idx] = o;
    X3b[idx] = bf16_rne(o);
}

// ---------- 5. energy GEMM + fused tanh/v-dot epilogue ----------
// A = [annots(fp32, cvt in staging) | Lconv(bf16)]: [65536, 544]
// B = Bbig bf16 [512, 544].  Output: wsal[nblk][bt] partial v.tanh sums.
__global__ __launch_bounds__(256, 2) void k_attn(
    const float* __restrict__ annots, const unsigned short* __restrict__ Lconv,
    const unsigned short* __restrict__ Bbig, const float* __restrict__ pqm,
    const float* __restrict__ ebias, const float* __restrict__ vw,
    float* __restrict__ wsal)
{
    __shared__ __align__(16) unsigned short As[128 * 32];
    __shared__ __align__(16) unsigned short Bs[128 * 32];
    __shared__ float red[2][128];
    const int tid = threadIdx.x;
    const int nblk = blockIdx.x & 3;
    const int mblk = blockIdx.x >> 2;
    const int btBase = mblk * 128;
    const int nBase = nblk * 128;
    const int b = btBase >> 10;
    const float* pqb = pqm + b * 512;

    const int lane = tid & 63, wave = tid >> 6;
    const int wrow = wave >> 1, wcol = wave & 1;
    const int c = lane & 15, qd = lane >> 4;
    const int sr = tid >> 2, sk = (tid & 3) * 8;

    const f32x4 fz = {0.f, 0.f, 0.f, 0.f};
    f32x4 acc[4][4];
#pragma unroll
    for (int i = 0; i < 4; ++i)
#pragma unroll
        for (int j = 0; j < 4; ++j) acc[i][j] = fz;

    for (int kc = 0; kc < 17; ++kc) {
        const int k0 = kc * 32;
        if (kc < 16) {
            const float* p0 = annots + (long)(btBase + sr) * 512 + k0 + sk;
            float4 v0 = *(const float4*)p0;
            float4 v1 = *(const float4*)(p0 + 4);
            uint4 u;
            u.x = pk2(v0.x, v0.y); u.y = pk2(v0.z, v0.w);
            u.z = pk2(v1.x, v1.y); u.w = pk2(v1.z, v1.w);
            *(uint4*)&As[sr * 32 + sk] = u;
            const float* p1 = p0 + 64 * 512;
            v0 = *(const float4*)p1;
            v1 = *(const float4*)(p1 + 4);
            uint4 u2;
            u2.x = pk2(v0.x, v0.y); u2.y = pk2(v0.z, v0.w);
            u2.z = pk2(v1.x, v1.y); u2.w = pk2(v1.z, v1.w);
            *(uint4*)&As[(sr + 64) * 32 + sk] = u2;
        } else {
            *(uint4*)&As[sr * 32 + sk] = *(const uint4*)&Lconv[(btBase + sr) * 32 + sk];
            *(uint4*)&As[(sr + 64) * 32 + sk] = *(const uint4*)&Lconv[(btBase + 64 + sr) * 32 + sk];
        }
        *(uint4*)&Bs[sr * 32 + sk] = *(const uint4*)&Bbig[(nBase + sr) * 544 + k0 + sk];
        *(uint4*)&Bs[(sr + 64) * 32 + sk] = *(const uint4*)&Bbig[(nBase + 64 + sr) * 544 + k0 + sk];
        __syncthreads();
        bf16x8 af[4], bfr[4];
#pragma unroll
        for (int i = 0; i < 4; ++i) af[i] = *(const bf16x8*)&As[(wrow * 64 + i * 16 + c) * 32 + qd * 8];
#pragma unroll
        for (int j = 0; j < 4; ++j) bfr[j] = *(const bf16x8*)&Bs[(wcol * 64 + j * 16 + c) * 32 + qd * 8];
#pragma unroll
        for (int i = 0; i < 4; ++i)
#pragma unroll
            for (int j = 0; j < 4; ++j) acc[i][j] = mfma16(af[i], bfr[j], acc[i][j]);
        __syncthreads();
    }
    // epilogue: e = tanh(acc + pq[b][col] + ebias[col]); partial += v[col]*e
    float pe[4], vv[4];
#pragma unroll
    for (int j = 0; j < 4; ++j) {
        int colg = nBase + wcol * 64 + j * 16 + c;
        pe[j] = pqb[colg] + ebias[colg];
        vv[j] = vw[colg];
    }
#pragma unroll
    for (int i = 0; i < 4; ++i)
#pragma unroll
        for (int r = 0; r < 4; ++r) {
            float p = 0.f;
#pragma unroll
            for (int j = 0; j < 4; ++j) {
                float e = tanh_fast(acc[i][j][r] + pe[j]);
                p += vv[j] * e;
            }
            p += __shfl_xor(p, 1);
            p += __shfl_xor(p, 2);
            p += __shfl_xor(p, 4);
            p += __shfl_xor(p, 8);
            if (c == 0) red[wcol][wrow * 64 + i * 16 + qd * 4 + r] = p;
        }
    __syncthreads();
    if (tid < 128) wsal[nblk * 65536 + btBase + tid] = red[0][tid] + red[1][tid];
}

// ---------- 6. normalize + context ----------
__global__ __launch_bounds__(256) void k_ctx(
    const float* __restrict__ annots, const float* __restrict__ wsal,
    const int* __restrict__ mask, float* __restrict__ out)
{
    __shared__ float al[1024];
    __shared__ float wsum[4];
    __shared__ float red[256];
    const int b = blockIdx.x >> 3;
    const int chunk = blockIdx.x & 7;
    const int tid = threadIdx.x;
    float lsum = 0.f;
#pragma unroll
    for (int p = 0; p < 4; ++p) {
        int t = p * 256 + tid;
        int bt = b * 1024 + t;
        float raw = wsal[bt] + wsal[65536 + bt] + wsal[131072 + bt] + wsal[196608 + bt];
        float s = (mask[bt] != 0) ? 1.f / (1.f + __expf(-raw)) : 0.f;
        al[t] = s;
        lsum += s;
    }
    for (int off = 32; off > 0; off >>= 1) lsum += __shfl_xor(lsum, off);
    if ((tid & 63) == 0) wsum[tid >> 6] = lsum;
    __syncthreads();
    const float tot = wsum[0] + wsum[1] + wsum[2] + wsum[3];
    const float inv = 1.f / tot;
    if (chunk == 0) {
#pragma unroll
        for (int p = 0; p < 4; ++p) {
            int t = p * 256 + tid;
            out[98304 + b * 1024 + t] = al[t] * inv;
        }
    }
    const int dq = tid & 63, tq = tid >> 6;
    const int d = chunk * 64 + dq;
    const float* ap = annots + (long)(b * 1024 + tq * 256) * 512 + d;
    float acc = 0.f;
#pragma unroll 4
    for (int t = 0; t < 256; ++t) acc += al[tq * 256 + t] * ap[(long)t * 512];
    red[tid] = acc;
    __syncthreads();
    if (tid < 64) {
        float s2 = red[tid] + red[64 + tid] + red[128 + tid] + red[192 + tid];
        out[65536 + b * 512 + chunk * 64 + tid] = s2 * inv;
    }
}

extern "C" void kernel_launch(void* const* d_in, const int* in_sizes, int n_in,
                              void* d_out, int out_size, void* d_ws, size_t ws_size,
                              hipStream_t stream) {
    const float* memory    = (const float*)d_in[0];
    const float* context   = (const float*)d_in[1];
    const float* rnn_state = (const float*)d_in[2];
    const float* annots    = (const float*)d_in[3];
    const float* atten     = (const float*)d_in[4];
    const int*   mask      = (const int*)d_in[5];
    // d_in[6] = t (unused)
    const float* W_ih   = (const float*)d_in[7];
    const float* W_hh   = (const float*)d_in[8];
    const float* b_ih   = (const float*)d_in[9];
    const float* b_hh   = (const float*)d_in[10];
    const float* conv_w = (const float*)d_in[11];
    const float* loc_w  = (const float*)d_in[12];
    const float* loc_b  = (const float*)d_in[13];
    const float* q_w    = (const float*)d_in[14];
    const float* q_b    = (const float*)d_in[15];
    const float* a_w    = (const float*)d_in[16];
    const float* a_b    = (const float*)d_in[17];
    const float* v_w    = (const float*)d_in[18];
    float* out = (float*)d_out;

    char* w8 = (char*)d_ws;
    unsigned short* Lconv = (unsigned short*)(w8 + 0);         //  4,194,304
    unsigned short* Bbig  = (unsigned short*)(w8 + 4194304);   //    557,056
    unsigned short* Wihb  = (unsigned short*)(w8 + 4751360);   //  6,291,456
    unsigned short* Whhb  = (unsigned short*)(w8 + 11042816);  //  6,291,456
    unsigned short* qwb   = (unsigned short*)(w8 + 17334272);  //  1,048,576
    unsigned short* X1b   = (unsigned short*)(w8 + 18382848);  //    131,072
    unsigned short* X2b   = (unsigned short*)(w8 + 18513920);  //    131,072
    unsigned short* X3b   = (unsigned short*)(w8 + 18644992);  //    131,072
    float*          Cgru  = (float*)(w8 + 18776064);           //  1,572,864
    float*          pq    = (float*)(w8 + 20348928);           //    131,072
    float*          ebias = (float*)(w8 + 20480000);           //      2,048
    float*          wsal  = (float*)(w8 + 20482048);           //  1,048,576

    k_convert<<<7057, 256, 0, stream>>>(W_ih, W_hh, q_w, rnn_state, memory, context,
                                        a_w, loc_w, a_b, loc_b,
                                        Wihb, Whhb, qwb, X2b, X1b, Bbig, ebias);
    k_conv<<<512, 256, 0, stream>>>(atten, conv_w, Lconv);
    k_gemm128<<<48, 256, 0, stream>>>(X1b, X2b, Wihb, Whhb, b_ih, b_hh,
                                      Cgru, 6144, 3072, 1024);
    k_gates<<<256, 256, 0, stream>>>(Cgru, rnn_state, out, X3b);
    k_gemm128<<<4, 256, 0, stream>>>(X3b, X3b, qwb, qwb, q_b, q_b,
                                     pq, 512, 0x40000000, 1024);
    k_attn<<<2048, 256, 0, stream>>>(annots, Lconv, Bbig, pq, ebias, v_w, wsal);
    k_ctx<<<512, 256, 0, stream>>>(annots, wsal, mask, out);
}

// Round 2
// 345.827 us; speedup vs baseline: 1.1134x; 1.1134x over previous
//
#include <hip/hip_runtime.h>

typedef float f32x4 __attribute__((ext_vector_type(4)));
typedef short bf16x8 __attribute__((ext_vector_type(8)));

// ---------- helpers ----------
__device__ __forceinline__ unsigned int pk2(float a, float b) {
    unsigned int ua = __float_as_uint(a); ua += 0x7FFFu + ((ua >> 16) & 1u);
    unsigned int ub = __float_as_uint(b); ub += 0x7FFFu + ((ub >> 16) & 1u);
    return __builtin_amdgcn_perm(ub, ua, 0x07060302u);
}
__device__ __forceinline__ unsigned short bf16_rne(float a) {
    unsigned int ua = __float_as_uint(a);
    ua += 0x7FFFu + ((ua >> 16) & 1u);
    return (unsigned short)(ua >> 16);
}
__device__ __forceinline__ float tanh_fast(float x) {
    float e = __expf(x + x);
    return 1.f - 2.f / (e + 1.f);
}
__device__ __forceinline__ f32x4 mfma16(bf16x8 a, bf16x8 b, f32x4 c) {
    return __builtin_amdgcn_mfma_f32_16x16x32_bf16(a, b, c, 0, 0, 0);
}
// async global->LDS, 16B per lane; LDS dest = wave base + lane*16
__device__ __forceinline__ void ald16(const void* g, void* l) {
    __builtin_amdgcn_global_load_lds(
        (const __attribute__((address_space(1))) unsigned int*)g,
        (__attribute__((address_space(3))) unsigned int*)l, 16, 0, 0);
}

// ---------- 1. prep: fp32->bf16 weight conversion + location conv ----------
#define Q_WIH   786432
#define Q_WHH   1572864
#define Q_QW    1703936
#define Q_X2    1720320
#define Q_X1    1736704
#define Q_BAW   1802240
#define Q_BLW   1806336
#define Q_EB    1806464
#define NCVT    7057

__global__ __launch_bounds__(256) void k_prep(
    const float* __restrict__ Wih, const float* __restrict__ Whh,
    const float* __restrict__ qw, const float* __restrict__ rnn_state,
    const float* __restrict__ memory, const float* __restrict__ context,
    const float* __restrict__ aw, const float* __restrict__ lw,
    const float* __restrict__ ab, const float* __restrict__ lb,
    const float* __restrict__ atten, const float* __restrict__ convw,
    unsigned short* __restrict__ Wihb, unsigned short* __restrict__ Whhb,
    unsigned short* __restrict__ qwb, unsigned short* __restrict__ X2b,
    unsigned short* __restrict__ X1b, unsigned short* __restrict__ Bbig,
    float* __restrict__ ebias, unsigned short* __restrict__ Lconv)
{
    __shared__ float att_s[2 * 160];
    __shared__ float cw_s[1984];
    const int tid = threadIdx.x;
    if (blockIdx.x < NCVT) {
        int q = blockIdx.x * 256 + tid;
        if (q >= Q_EB) return;
        if (q < Q_WIH) {
            int i = q * 4;
            float4 v = *(const float4*)(Wih + i);
            uint2 u; u.x = pk2(v.x, v.y); u.y = pk2(v.z, v.w);
            *(uint2*)(Wihb + i) = u;
        } else if (q < Q_WHH) {
            int i = (q - Q_WIH) * 4;
            float4 v = *(const float4*)(Whh + i);
            uint2 u; u.x = pk2(v.x, v.y); u.y = pk2(v.z, v.w);
            *(uint2*)(Whhb + i) = u;
        } else if (q < Q_QW) {
            int i = (q - Q_WHH) * 4;
            float4 v = *(const float4*)(qw + i);
            uint2 u; u.x = pk2(v.x, v.y); u.y = pk2(v.z, v.w);
            *(uint2*)(qwb + i) = u;
        } else if (q < Q_X2) {
            int i = (q - Q_QW) * 4;
            float4 v = *(const float4*)(rnn_state + i);
            uint2 u; u.x = pk2(v.x, v.y); u.y = pk2(v.z, v.w);
            *(uint2*)(X2b + i) = u;
        } else if (q < Q_X1) {
            int i = (q - Q_X2) * 4;
            int b = i >> 10, c = i & 1023;
            const float* s = (c < 512) ? (memory + b * 512 + c) : (context + b * 512 + (c - 512));
            float4 v = *(const float4*)s;
            uint2 u; u.x = pk2(v.x, v.y); u.y = pk2(v.z, v.w);
            *(uint2*)(X1b + i) = u;
        } else if (q < Q_BAW) {
            int i = (q - Q_X1) * 4;
            int a = i >> 9, c = i & 511;
            float4 v = *(const float4*)(aw + a * 512 + c);
            uint2 u; u.x = pk2(v.x, v.y); u.y = pk2(v.z, v.w);
            *(uint2*)(Bbig + a * 544 + c) = u;
        } else if (q < Q_BLW) {
            int i = (q - Q_BAW) * 4;
            int a = i >> 5, c = i & 31;
            float4 v = *(const float4*)(lw + a * 32 + c);
            uint2 u; u.x = pk2(v.x, v.y); u.y = pk2(v.z, v.w);
            *(uint2*)(Bbig + a * 544 + 512 + c) = u;
        } else {
            int i = (q - Q_BLW) * 4;
            float4 va = *(const float4*)(ab + i);
            float4 vb = *(const float4*)(lb + i);
            float4 r; r.x = va.x + vb.x; r.y = va.y + vb.y; r.z = va.z + vb.z; r.w = va.w + vb.w;
            *(float4*)(ebias + i) = r;
        }
    } else {
        const int bid = blockIdx.x - NCVT;
        const int b = bid >> 3;
        const int tbase = (bid & 7) * 128;
        for (int i = tid; i < 320; i += 256) {
            int c = i / 160, j = i % 160;
            float v = 0.f;
            int pos = tbase - 15 + j;
            if (j < 158 && pos >= 0 && pos < 1024) v = atten[b * 2048 + c * 1024 + pos];
            att_s[c * 160 + j] = v;
        }
        for (int i = tid; i < 1984; i += 256) cw_s[i] = convw[i];
        __syncthreads();
        const int f = tid & 31, tq = tid >> 5;
        float acc[16];
#pragma unroll
        for (int i = 0; i < 16; ++i) acc[i] = 0.f;
        for (int c = 0; c < 2; ++c) {
            for (int k = 0; k < 31; ++k) {
                float w = cw_s[f * 62 + c * 31 + k];
                int base = c * 160 + tq * 16 + k;
#pragma unroll
                for (int ti = 0; ti < 16; ++ti) acc[ti] += w * att_s[base + ti];
            }
        }
#pragma unroll
        for (int ti = 0; ti < 16; ++ti) {
            int t = tbase + tq * 16 + ti;
            Lconv[(b * 1024 + t) * 32 + f] = bf16_rne(acc[ti]);
        }
    }
}

// ---------- 2. M=64 K-split GEMM, N-tile 128: C[ks][64][N] partial = A @ B^T ----------
// grid = nTiles * Ksplit;  XOR-swizzled LDS (chunk ^= (row>>1)&3), global_load_lds staging
__global__ __launch_bounds__(256, 4) void k_gemm_ks(
    const unsigned short* __restrict__ A1, const unsigned short* __restrict__ A2,
    const unsigned short* __restrict__ B1, const unsigned short* __restrict__ B2,
    float* __restrict__ C, int N, int nTiles, int n_split, int K, int Klen)
{
    __shared__ __align__(16) unsigned short As[64 * 32];
    __shared__ __align__(16) unsigned short Bs[128 * 32];
    const int tid = threadIdx.x;
    const int nb = blockIdx.x % nTiles;
    const int ks = blockIdx.x / nTiles;
    const int nBase = nb * 128;
    const bool use2 = nBase >= n_split;
    const unsigned short* A = use2 ? A2 : A1;
    const unsigned short* B = use2 ? B2 : B1;
    const int brow0 = nBase - (use2 ? n_split : 0);
    const int lane = tid & 63, w = tid >> 6;
    const int c = lane & 15, qd = lane >> 4;
    const int lr = lane >> 2;
    const int swzl = ((lane & 3) ^ ((lr >> 1) & 3)) * 8;  // logical-chunk elem offset for linear LDS dest

    const f32x4 fz = {0.f, 0.f, 0.f, 0.f};
    f32x4 acc[4][2];
#pragma unroll
    for (int i = 0; i < 4; ++i) { acc[i][0] = fz; acc[i][1] = fz; }

    const int k0b = ks * Klen;
    const int nkc = Klen >> 5;
    for (int kc = 0; kc < nkc; ++kc) {
        const int k0 = k0b + kc * 32;
        ald16(A + (size_t)(w * 16 + lr) * K + k0 + swzl, &As[w * 512]);
        ald16(B + (size_t)(brow0 + w * 16 + lr) * K + k0 + swzl, &Bs[w * 512]);
        ald16(B + (size_t)(brow0 + 64 + w * 16 + lr) * K + k0 + swzl, &Bs[2048 + w * 512]);
        __syncthreads();
        const int rdoff = (qd ^ ((c >> 1) & 3)) * 8;
        bf16x8 af[4];
#pragma unroll
        for (int i = 0; i < 4; ++i) af[i] = *(const bf16x8*)&As[(i * 16 + c) * 32 + rdoff];
#pragma unroll
        for (int j = 0; j < 2; ++j) {
            bf16x8 bj = *(const bf16x8*)&Bs[(w * 32 + j * 16 + c) * 32 + rdoff];
#pragma unroll
            for (int i = 0; i < 4; ++i) acc[i][j] = mfma16(af[i], bj, acc[i][j]);
        }
        __syncthreads();
    }
    float* Cp = C + (size_t)ks * 64 * N;
#pragma unroll
    for (int i = 0; i < 4; ++i)
#pragma unroll
        for (int r = 0; r < 4; ++r) {
            int row = i * 16 + qd * 4 + r;
#pragma unroll
            for (int j = 0; j < 2; ++j) {
                int col = nBase + w * 32 + j * 16 + c;
                Cp[row * N + col] = acc[i][j][r];
            }
        }
}

// ---------- 3. GRU gates (sums K-split partials, adds biases) ----------
__global__ __launch_bounds__(256) void k_gates(
    const float* __restrict__ Cg, const float* __restrict__ h0,
    const float* __restrict__ bih, const float* __restrict__ bhh,
    float* __restrict__ outv, unsigned short* __restrict__ X3b)
{
    int idx = blockIdx.x * 256 + threadIdx.x;
    int b = idx >> 10, h = idx & 1023;
    const float* g0 = Cg + b * 6144;
    const float* g1 = Cg + 393216 + b * 6144;
    float ir = g0[h] + g1[h] + bih[h];
    float iz = g0[h + 1024] + g1[h + 1024] + bih[h + 1024];
    float inn = g0[h + 2048] + g1[h + 2048] + bih[h + 2048];
    float hr = g0[h + 3072] + g1[h + 3072] + bhh[h];
    float hz = g0[h + 4096] + g1[h + 4096] + bhh[h + 1024];
    float hn = g0[h + 5120] + g1[h + 5120] + bhh[h + 2048];
    float r = 1.f / (1.f + __expf(-(ir + hr)));
    float z = 1.f / (1.f + __expf(-(iz + hz)));
    float n = tanh_fast(inn + r * hn);
    float o = (1.f - z) * n + z * h0[idx];
    outv[idx] = o;
    X3b[idx] = bf16_rne(o);
}

// ---------- 4. energy GEMM, M-tile 64 x full N=512, fused tanh/v-dot ----------
// A = [annots bf16 (inline cvt) | Lconv] : K=544;  B = Bbig [512][544]
// annots fetched from HBM exactly once; B is L2-resident.
__global__ __launch_bounds__(256, 2) void k_attn(
    const float* __restrict__ annots, const unsigned short* __restrict__ Lconv,
    const unsigned short* __restrict__ Bbig, const float* __restrict__ pqP,
    const float* __restrict__ qb, const float* __restrict__ ebias,
    const float* __restrict__ vw, float* __restrict__ wsal)
{
    __shared__ __align__(16) unsigned short As[64 * 32];    //  4 KB
    __shared__ __align__(16) unsigned short Bs[512 * 32];   // 32 KB
    __shared__ float red[4][64];
    const int tid = threadIdx.x;
    const int btBase = blockIdx.x * 64;
    const int b = btBase >> 10;
    const int lane = tid & 63, w = tid >> 6;
    const int c = lane & 15, qd = lane >> 4;
    const int lr = lane >> 2;
    const int swzl = ((lane & 3) ^ ((lr >> 1) & 3)) * 8;
    const int arow = tid >> 2, alc = tid & 3;
    const int apofs = (alc ^ ((arow >> 1) & 3)) * 8;

    const f32x4 fz = {0.f, 0.f, 0.f, 0.f};
    f32x4 acc[4][8];
#pragma unroll
    for (int i = 0; i < 4; ++i)
#pragma unroll
        for (int j = 0; j < 8; ++j) acc[i][j] = fz;

    for (int kc = 0; kc < 17; ++kc) {
        const int k0 = kc * 32;
        // B: 512 rows x 32k, 8 wave-issues of 16 rows each
#pragma unroll
        for (int s = 0; s < 8; ++s)
            ald16(Bbig + (size_t)(s * 64 + w * 16 + lr) * 544 + k0 + swzl,
                  &Bs[s * 2048 + w * 512]);
        if (kc < 16) {
            // A: 64 rows x 32k fp32 -> bf16 inline
            const float* p = annots + (size_t)(btBase + arow) * 512 + k0 + alc * 8;
            float4 v0 = *(const float4*)p;
            float4 v1 = *(const float4*)(p + 4);
            uint4 u;
            u.x = pk2(v0.x, v0.y); u.y = pk2(v0.z, v0.w);
            u.z = pk2(v1.x, v1.y); u.w = pk2(v1.z, v1.w);
            *(uint4*)&As[arow * 32 + apofs] = u;
        } else {
            ald16(Lconv + (size_t)(btBase + w * 16 + lr) * 32 + swzl, &As[w * 512]);
        }
        __syncthreads();
        const int rdoff = (qd ^ ((c >> 1) & 3)) * 8;
        bf16x8 af[4];
#pragma unroll
        for (int i = 0; i < 4; ++i) af[i] = *(const bf16x8*)&As[(i * 16 + c) * 32 + rdoff];
#pragma unroll
        for (int j = 0; j < 8; ++j) {
            bf16x8 bj = *(const bf16x8*)&Bs[(w * 128 + j * 16 + c) * 32 + rdoff];
#pragma unroll
            for (int i = 0; i < 4; ++i) acc[i][j] = mfma16(af[i], bj, acc[i][j]);
        }
        __syncthreads();
    }
    // epilogue: raw_align[t] = sum_col v[col]*tanh(acc + pq[b][col] + qb + ebias)
    float pe[8], vv[8];
#pragma unroll
    for (int j = 0; j < 8; ++j) {
        int colg = w * 128 + j * 16 + c;
        pe[j] = pqP[b * 512 + colg] + pqP[32768 + b * 512 + colg] + qb[colg] + ebias[colg];
        vv[j] = vw[colg];
    }
#pragma unroll
    for (int i = 0; i < 4; ++i)
#pragma unroll
        for (int r = 0; r < 4; ++r) {
            float p = 0.f;
#pragma unroll
            for (int j = 0; j < 8; ++j)
                p += vv[j] * tanh_fast(acc[i][j][r] + pe[j]);
            p += __shfl_xor(p, 1);
            p += __shfl_xor(p, 2);
            p += __shfl_xor(p, 4);
            p += __shfl_xor(p, 8);
            if (c == 0) red[w][i * 16 + qd * 4 + r] = p;
        }
    __syncthreads();
    if (tid < 64)
        wsal[btBase + tid] = red[0][tid] + red[1][tid] + red[2][tid] + red[3][tid];
}

// ---------- 5. normalize + context ----------
__global__ __launch_bounds__(256) void k_ctx(
    const float* __restrict__ annots, const float* __restrict__ wsal,
    const int* __restrict__ mask, float* __restrict__ out)
{
    __shared__ float al[1024];
    __shared__ float wsum[4];
    __shared__ float red[256];
    const int b = blockIdx.x >> 3;
    const int chunk = blockIdx.x & 7;
    const int tid = threadIdx.x;
    float lsum = 0.f;
#pragma unroll
    for (int p = 0; p < 4; ++p) {
        int t = p * 256 + tid;
        int bt = b * 1024 + t;
        float raw = wsal[bt];
        float s = (mask[bt] != 0) ? 1.f / (1.f + __expf(-raw)) : 0.f;
        al[t] = s;
        lsum += s;
    }
    for (int off = 32; off > 0; off >>= 1) lsum += __shfl_xor(lsum, off);
    if ((tid & 63) == 0) wsum[tid >> 6] = lsum;
    __syncthreads();
    const float tot = wsum[0] + wsum[1] + wsum[2] + wsum[3];
    const float inv = 1.f / tot;
    if (chunk == 0) {
#pragma unroll
        for (int p = 0; p < 4; ++p) {
            int t = p * 256 + tid;
            out[98304 + b * 1024 + t] = al[t] * inv;
        }
    }
    const int dq = tid & 63, tq = tid >> 6;
    const int d = chunk * 64 + dq;
    const float* ap = annots + (size_t)(b * 1024 + tq * 256) * 512 + d;
    float acc = 0.f;
#pragma unroll 4
    for (int t = 0; t < 256; ++t) acc += al[tq * 256 + t] * ap[(size_t)t * 512];
    red[tid] = acc;
    __syncthreads();
    if (tid < 64) {
        float s2 = red[tid] + red[64 + tid] + red[128 + tid] + red[192 + tid];
        out[65536 + b * 512 + chunk * 64 + tid] = s2 * inv;
    }
}

extern "C" void kernel_launch(void* const* d_in, const int* in_sizes, int n_in,
                              void* d_out, int out_size, void* d_ws, size_t ws_size,
                              hipStream_t stream) {
    const float* memory    = (const float*)d_in[0];
    const float* context   = (const float*)d_in[1];
    const float* rnn_state = (const float*)d_in[2];
    const float* annots    = (const float*)d_in[3];
    const float* atten     = (const float*)d_in[4];
    const int*   mask      = (const int*)d_in[5];
    const float* W_ih   = (const float*)d_in[7];
    const float* W_hh   = (const float*)d_in[8];
    const float* b_ih   = (const float*)d_in[9];
    const float* b_hh   = (const float*)d_in[10];
    const float* conv_w = (const float*)d_in[11];
    const float* loc_w  = (const float*)d_in[12];
    const float* loc_b  = (const float*)d_in[13];
    const float* q_w    = (const float*)d_in[14];
    const float* q_b    = (const float*)d_in[15];
    const float* a_w    = (const float*)d_in[16];
    const float* a_b    = (const float*)d_in[17];
    const float* v_w    = (const float*)d_in[18];
    float* out = (float*)d_out;

    char* w8 = (char*)d_ws;
    unsigned short* Lconv = (unsigned short*)(w8 + 0);         //  4,194,304
    unsigned short* Bbig  = (unsigned short*)(w8 + 4194304);   //    557,056
    unsigned short* Wihb  = (unsigned short*)(w8 + 4751360);   //  6,291,456
    unsigned short* Whhb  = (unsigned short*)(w8 + 11042816);  //  6,291,456
    unsigned short* qwb   = (unsigned short*)(w8 + 17334272);  //  1,048,576
    unsigned short* X1b   = (unsigned short*)(w8 + 18382848);  //    131,072
    unsigned short* X2b   = (unsigned short*)(w8 + 18513920);  //    131,072
    unsigned short* X3b   = (unsigned short*)(w8 + 18644992);  //    131,072
    float*          Cgru  = (float*)(w8 + 18776064);           //  3,145,728 (2 K-split partials)
    // pq partials + wsal alias the (dead-after-k_gates) Cgru region:
    float*          pqP   = (float*)(w8 + 18776064);           //    262,144 (2 partials)
    float*          wsal  = (float*)(w8 + 19038208);           //    262,144
    float*          ebias = (float*)(w8 + 21921792);           //      2,048

    k_prep<<<NCVT + 512, 256, 0, stream>>>(W_ih, W_hh, q_w, rnn_state, memory, context,
                                           a_w, loc_w, a_b, loc_b, atten, conv_w,
                                           Wihb, Whhb, qwb, X2b, X1b, Bbig, ebias, Lconv);
    // GRU: N=6144 (gi|gh), 48 N-tiles x K-split2 = 96 blocks
    k_gemm_ks<<<96, 256, 0, stream>>>(X1b, X2b, Wihb, Whhb, Cgru, 6144, 48, 3072, 1024, 512);
    k_gates<<<256, 256, 0, stream>>>(Cgru, rnn_state, b_ih, b_hh, out, X3b);
    // pq: N=512, 4 N-tiles x K-split2 = 8 blocks
    k_gemm_ks<<<8, 256, 0, stream>>>(X3b, X3b, qwb, qwb, pqP, 512, 4, 0x40000000, 1024, 512);
    k_attn<<<1024, 256, 0, stream>>>(annots, Lconv, Bbig, pqP, q_b, ebias, v_w, wsal);
    k_ctx<<<512, 256, 0, stream>>>(annots, wsal, mask, out);
}